// Round 6
// baseline (381.859 us; speedup 1.0000x reference)
//
#include <hip/hip_runtime.h>
#include <math.h>

#define BB 8
#define NPTS 80000
#define KK 5
#define FF 20
#define GG 192                 // blocks per batch -> 1536 blocks = 6 blocks/CU (needs VGPR<=64)
#define TILE 64                // one point per lane (2-pt variant regressed, r5)
#define NTILES (NPTS / TILE)   // 1250, exact
#define PSTRIDE 48             // padded partial row: 20 s1 + 20 s2 + 1 s0 + pad

// workspace layout (float offsets) -- small params/coefs only
#define WS_CM 0
#define WS_CV 800
#define WS_CP 1600
#define WS_A  1640
#define WS_D  1680
#define WS_E  2480

// Raw barrier: drain LDS ops (cross-wave lls visibility) but leave global
// loads (prefetch touches) in flight. __syncthreads() would emit
// s_waitcnt vmcnt(0) and expose the prefetch latency AT the barrier.
#define WAIT_BAR() asm volatile("s_waitcnt lgkmcnt(0)\n\ts_barrier" ::: "memory")

__device__ __forceinline__ float rfl(float x) {   // lane0 value -> SGPR
    return __uint_as_float(__builtin_amdgcn_readfirstlane(__float_as_uint(x)));
}

// ---- E-step with fused M-step prologue ----
// MODE 0: coefs from raw inputs (first E-step); accumulate partials -> pout
// MODE 1: coefs rebuilt from PREVIOUS iteration's partials (pin) = fused M-step
// MODE 3: coefs from ws (written by update_kernel); write ll/post outputs
// pin/pout ping-pong: never alias (prologue reads pin while others write pout).
template <int MODE>
__global__ __launch_bounds__(320) void estep_kernel(
        const float* __restrict__ data,
        const float* __restrict__ in_means, const float* __restrict__ in_var,
        const float* __restrict__ in_pi,
        const float* __restrict__ ws,
        const float* __restrict__ pin, float* __restrict__ pout,
        float* __restrict__ out_ll, float* __restrict__ out_post) {
    __shared__ float lls[2][KK][TILE];        // 2.5 KB: z exchange, double-buffered
    __shared__ float coefs[KK][2 * FF + 1];   // dk | ek | A broadcast buffer
    __shared__ float s0s[KK];

    const int b    = blockIdx.x / GG;
    const int g    = blockIdx.x % GG;
    const int tid  = threadIdx.x;
    const int w    = __builtin_amdgcn_readfirstlane(tid >> 6);   // cluster k
    const int lane = tid & 63;
    const int bk   = b * KK + w;

    float dk[FF], ek[FF];   // wave-uniform -> SGPRs
    float Ak;

    if (MODE == 3) {
        Ak = (ws + WS_A)[bk];
#pragma unroll
        for (int f = 0; f < FF; ++f) {
            dk[f] = (ws + WS_D)[bk * FF + f];
            ek[f] = (ws + WS_E)[bk * FF + f];
        }
    } else {
        if (MODE == 0) {
            float t1 = 0.f, t2 = 0.f;
            if (lane < FF) {
                float v = in_var[bk * FF + lane];
                float m = in_means[bk * FF + lane];
                float ic = 1.f / (v + 1e-6f);
                coefs[w][lane]      = ic * m;
                coefs[w][FF + lane] = -0.5f * ic;
                t1 = logf(6.283185307179586f * v);
                t2 = ic * m * m;
            }
#pragma unroll
            for (int off = 1; off < 64; off <<= 1) {
                t1 += __shfl_xor(t1, off);
                t2 += __shfl_xor(t2, off);
            }
            if (lane == 0)
                coefs[w][2 * FF] = logf(in_pi[bk]) - 0.5f * t1 - 0.5f * t2;
            __syncthreads();
        } else {
            // MODE 1: fused M-step. Every block redundantly reduces pin for
            // its batch: wave w, lane<48 sums slot `lane` over GG rows
            // (coalesced 192B rows, 2 split accumulators).
            float sv = 0.f;
            if (lane < PSTRIDE) {
                const float* base = pin + (size_t)bk * GG * PSTRIDE + lane;
                float a0 = 0.f, a1 = 0.f;
                for (int gg = 0; gg < GG; gg += 2) {
                    a0 += base[(size_t)(gg    ) * PSTRIDE];
                    a1 += base[(size_t)(gg + 1) * PSTRIDE];
                }
                sv = a0 + a1;
            }
            float s0 = __shfl(sv, 2 * FF);
            if (lane == 0) s0s[w] = s0;
            __syncthreads();
            float tot = s0s[0] + s0s[1] + s0s[2] + s0s[3] + s0s[4];
            float den = s0 + 1e-7f;
            float m   = sv / den;                      // lanes 0..19: S1[f]/den
            float s2f = __shfl(sv, FF + (lane % FF));  // S2[f]
            float var = (s2f - 2.f * m * sv + m * m * s0) / den + 1e-6f;
            float pr  = (s0 / (float)NPTS) / fmaxf(tot / (float)NPTS, 1e-12f);
            float ic  = 1.f / (var + 1e-6f);
            float t1 = 0.f, t2 = 0.f;
            if (lane < FF) {
                coefs[w][lane]      = ic * m;
                coefs[w][FF + lane] = -0.5f * ic;
                t1 = logf(6.283185307179586f * var);
                t2 = ic * m * m;
            }
#pragma unroll
            for (int off = 1; off < 64; off <<= 1) {
                t1 += __shfl_xor(t1, off);
                t2 += __shfl_xor(t2, off);
            }
            if (lane == 0)
                coefs[w][2 * FF] = logf(pr) - 0.5f * t1 - 0.5f * t2;
            __syncthreads();
        }
#pragma unroll
        for (int f = 0; f < FF; ++f) {
            dk[f] = rfl(coefs[w][f]);
            ek[f] = rfl(coefs[w][FF + f]);
        }
        Ak = rfl(coefs[w][2 * FF]);
    }

    constexpr bool ACC = (MODE != 3);
    float s0a = 0.f, s1[FF], s2[FF];
    if (ACC) {
#pragma unroll
        for (int f = 0; f < FF; ++f) { s1[f] = 0.f; s2[f] = 0.f; }
    }

    const float* dbase = data + (size_t)b * NPTS * FF;
    int pb = 0;
    float pf_hold = 0.f;   // touch issued LAST iteration; consumed one iter late
                           // so its waitcnt is counted (near-free), not a drain

    for (int t = g; t < NTILES; t += GG) {
        // lane-owned point: 20 floats -> 5 x dwordx4 (L1-hit: touched last iter)
        const float* xp = dbase + ((size_t)t * TILE + lane) * FF;
        float4 xa = ((const float4*)xp)[0];
        float4 xb = ((const float4*)xp)[1];
        float4 xc = ((const float4*)xp)[2];
        float4 xd = ((const float4*)xp)[3];
        float4 xe = ((const float4*)xp)[4];

        // prefetch touch for tile t+GG: one b32 per lane warms every 80 B of
        // the next 5 KB tile; stays outstanding across WAIT_BAR and the whole
        // iteration (consumed NEXT iteration via pf_hold).
        float pf = 0.f;
        const int tn = t + GG;
        if (tn < NTILES) pf = dbase[((size_t)tn * TILE + lane) * FF];

        float x[FF];
        x[0]=xa.x; x[1]=xa.y; x[2]=xa.z; x[3]=xa.w;
        x[4]=xb.x; x[5]=xb.y; x[6]=xb.z; x[7]=xb.w;
        x[8]=xc.x; x[9]=xc.y; x[10]=xc.z; x[11]=xc.w;
        x[12]=xd.x; x[13]=xd.y; x[14]=xd.z; x[15]=xd.w;
        x[16]=xe.x; x[17]=xe.y; x[18]=xe.z; x[19]=xe.w;

        float za = 0.f, zb = 0.f;    // two chains for ILP
#pragma unroll
        for (int f = 0; f < FF; f += 2) {
            za = fmaf(x[f],     fmaf(ek[f],     x[f],     dk[f]),     za);
            zb = fmaf(x[f + 1], fmaf(ek[f + 1], x[f + 1], dk[f + 1]), zb);
        }
        float z = Ak + za + zb;

        lls[pb][w][lane] = z;
        WAIT_BAR();                  // lls visible; global loads still in flight

        float l0 = lls[pb][0][lane], l1 = lls[pb][1][lane], l2 = lls[pb][2][lane],
              l3 = lls[pb][3][lane], l4 = lls[pb][4][lane];
        float mx = fmaxf(fmaxf(fmaxf(l0, l1), fmaxf(l2, l3)), l4);
        float e0 = __expf(l0 - mx), e1 = __expf(l1 - mx), e2 = __expf(l2 - mx),
              e3 = __expf(l3 - mx), e4 = __expf(l4 - mx);
        float inv = 1.f / (e0 + e1 + e2 + e3 + e4);
        float ew  = (w == 0) ? e0 : (w == 1) ? e1 : (w == 2) ? e2 : (w == 3) ? e3 : e4;
        float post = ew * inv;

        if (!ACC) {
            size_t o = ((size_t)b * NPTS + (size_t)t * TILE + lane) * KK + w;
            out_ll[o]   = z;
            out_post[o] = post;
        } else {
            s0a += post;
#pragma unroll
            for (int f = 0; f < FF; ++f) {
                float px = post * x[f];
                s1[f] += px;
                s2[f] = fmaf(px, x[f], s2[f]);
            }
        }
        asm volatile("" :: "v"(pf_hold));   // consume PREVIOUS touch (counted wait)
        pf_hold = pf;
        pb ^= 1;
    }
    asm volatile("" :: "v"(pf_hold));

    if (ACC) {
#pragma unroll
        for (int off = 32; off > 0; off >>= 1) {
            s0a += __shfl_down(s0a, off);
#pragma unroll
            for (int f = 0; f < FF; ++f) {
                s1[f] += __shfl_down(s1[f], off);
                s2[f] += __shfl_down(s2[f], off);
            }
        }
        if (lane == 0) {
            float* row = pout + ((size_t)bk * GG + g) * PSTRIDE;
#pragma unroll
            for (int f = 0; f < FF; ++f) { row[f] = s1[f]; row[FF + f] = s2[f]; }
            row[2 * FF] = s0a;
        }
    }
}

// ---- final reduce + M-step: writes om/ov/op AND ws coefs for the last E-step ----
__global__ __launch_bounds__(512) void update_kernel(const float* __restrict__ partials,
                                                     float* __restrict__ ws,
                                                     float* __restrict__ om,
                                                     float* __restrict__ ov,
                                                     float* __restrict__ op) {
    __shared__ float shA[8][PSTRIDE];
    __shared__ float shB[8 * KK];
    const int bk   = blockIdx.x;          // b*KK + k
    const int b    = bk / KK;
    const int tid  = threadIdx.x;
    const int w8   = tid >> 6;
    const int lane = tid & 63;

    if (lane < PSTRIDE) {
        const float* base = partials + (size_t)bk * GG * PSTRIDE + lane;
        float sv = 0.f;
        for (int gg = w8; gg < GG; gg += 8) sv += base[(size_t)gg * PSTRIDE];
        shA[w8][lane] = sv;
    }
    if (tid < 8 * KK) {
        const int kp = tid >> 3, j = tid & 7;
        const float* cb = partials + (size_t)(b * KK + kp) * GG * PSTRIDE + 2 * FF;
        float s = 0.f;
        for (int gg = j; gg < GG; gg += 8) s += cb[(size_t)gg * PSTRIDE];
        shB[tid] = s;
    }
    __syncthreads();

    if (tid < 64) {
        float svt = 0.f;
        if (lane < PSTRIDE) {
            svt = (shA[0][lane] + shA[1][lane]) + (shA[2][lane] + shA[3][lane])
                + (shA[4][lane] + shA[5][lane]) + (shA[6][lane] + shA[7][lane]);
        }

        float tb = (lane < 8 * KK) ? shB[lane] : 0.f;
#pragma unroll
        for (int off = 32; off > 0; off >>= 1) tb += __shfl_xor(tb, off);

        float s0  = __shfl(svt, 2 * FF);
        float den = s0 + 1e-7f;
        float m   = svt / den;
        float s2f = __shfl(svt, FF + (lane % FF));
        float var = (s2f - 2.f * m * svt + m * m * s0) / den + 1e-6f;

        if (lane < FF) {
            om[bk * FF + lane] = m;
            ov[bk * FF + lane] = var;
        }

        float pr = (s0 / (float)NPTS) / fmaxf(tb / (float)NPTS, 1e-12f);
        if (lane == 0) op[bk] = pr;

        float ic = 1.f / (var + 1e-6f);
        if (lane < FF) {
            (ws + WS_D)[bk * FF + lane] = ic * m;
            (ws + WS_E)[bk * FF + lane] = -0.5f * ic;
        }
        float t1 = (lane < FF) ? logf(6.283185307179586f * var) : 0.f;
        float t2 = (lane < FF) ? ic * m * m : 0.f;
#pragma unroll
        for (int off = 1; off < 64; off <<= 1) {
            t1 += __shfl_xor(t1, off);
            t2 += __shfl_xor(t2, off);
        }
        if (lane == 0)
            (ws + WS_A)[bk] = logf(pr) - 0.5f * t1 - 0.5f * t2;
    }
}

extern "C" void kernel_launch(void* const* d_in, const int* in_sizes, int n_in,
                              void* d_out, int out_size, void* d_ws, size_t ws_size,
                              hipStream_t stream) {
    const float* data     = (const float*)d_in[0];
    const float* in_means = (const float*)d_in[1];
    const float* in_var   = (const float*)d_in[2];
    const float* in_pi    = (const float*)d_in[3];
    float* ws  = (float*)d_ws;
    float* out = (float*)d_out;

    float* out_ll   = out;
    float* out_post = out + (size_t)BB * NPTS * KK;
    float* om       = out + 2 * (size_t)BB * NPTS * KK;
    float* ov       = om + BB * KK * FF;
    float* op       = ov + BB * KK * FF;

    // ping-pong partial buffers (1.47 MB each) in the not-yet-needed ll region
    // (12.8 MB); the final E-step fully overwrites both.
    float* P0 = out_ll;
    float* P1 = out_ll + 400000;

    // it0: coefs from inputs, write P0
    estep_kernel<0><<<BB * GG, 320, 0, stream>>>(data, in_means, in_var, in_pi,
                                                 ws, nullptr, P0, nullptr, nullptr);
    // it1..4: fused update of previous partials; ping-pong P0/P1
    estep_kernel<1><<<BB * GG, 320, 0, stream>>>(data, nullptr, nullptr, nullptr,
                                                 ws, P0, P1, nullptr, nullptr);
    estep_kernel<1><<<BB * GG, 320, 0, stream>>>(data, nullptr, nullptr, nullptr,
                                                 ws, P1, P0, nullptr, nullptr);
    estep_kernel<1><<<BB * GG, 320, 0, stream>>>(data, nullptr, nullptr, nullptr,
                                                 ws, P0, P1, nullptr, nullptr);
    estep_kernel<1><<<BB * GG, 320, 0, stream>>>(data, nullptr, nullptr, nullptr,
                                                 ws, P1, P0, nullptr, nullptr);
    // final M-step (it4 partials in P0): writes om/ov/op + ws coefs
    update_kernel<<<BB * KK, 512, 0, stream>>>(P0, ws, om, ov, op);
    // final E-step: write ll/post with post-loop params
    estep_kernel<3><<<BB * GG, 320, 0, stream>>>(data, nullptr, nullptr, nullptr,
                                                 ws, nullptr, nullptr, out_ll, out_post);
}

// Round 7
// 367.285 us; speedup vs baseline: 1.0397x; 1.0397x over previous
//
#include <hip/hip_runtime.h>
#include <math.h>

#define BB 8
#define NPTS 80000
#define KK 5
#define FF 20
#define GB 128                  // blocks per batch (256 thr = 4 waves) -> 1024 blocks
#define WPB (GB * 4)            // waves per batch = 512
#define PPT 12                  // points per wave-tile (60 active lanes = 12 pts x 5 clusters)
#define NT12 ((NPTS + PPT - 1) / PPT)   // 6667 tiles (last tile has 8 points)
#define PSTRIDE 48              // padded partial row: 20 s1 + 20 s2 + 1 s0 + pad

// workspace layout (float offsets)
#define WS_A  0      // [BB*KK]
#define WS_D  40     // [BB*KK*FF]
#define WS_E  840    // [BB*KK*FF]

// ---- E-step: BARRIER-FREE. lane = cluster*12 + point ----
// All six prior structures (5 waves/block + LDS z-exchange + per-tile barrier)
// pinned at 41-60 us with VALU ~26%: the barrier lockstep is the limiter.
// Here the 5-cluster softmax exchange happens INSIDE one wave via ds_bpermute
// (__shfl with per-lane src), so every wave is an independent pipeline:
// no LDS data path, no barriers, nothing cross-wave. Coefs are per-lane VGPRs.
// MODE 0: coefs computed from raw inputs (lane-redundant, prologue-only)
// MODE 1: coefs read from ws (written by update_kernel); accumulate partials
// MODE 3: coefs read from ws; write ll/post outputs
template <int MODE>
__global__ __launch_bounds__(256) void estep_kernel(
        const float* __restrict__ data,
        const float* __restrict__ in_means, const float* __restrict__ in_var,
        const float* __restrict__ in_pi,
        const float* __restrict__ ws,
        float* __restrict__ pout,
        float* __restrict__ out_ll, float* __restrict__ out_post) {
    const int b    = blockIdx.x / GB;
    const int blk  = blockIdx.x % GB;
    const int tid  = threadIdx.x;
    const int lane = tid & 63;
    const int wv   = blk * 4 + (tid >> 6);    // wave id within batch, 0..WPB-1
    const int g    = lane / PPT;              // cluster group (g==5 -> idle lanes 60-63)
    const int j    = lane % PPT;              // point-in-tile
    const bool act = (g < KK);
    const int gc   = act ? g : KK - 1;        // clamp idle lanes (avoid OOB coef reads)
    const int bk   = b * KK + gc;

    // per-lane coefs (VGPRs; 12-lane-broadcast loads)
    float dk[FF], ek[FF], Ak;
    if (MODE == 0) {
        float sumlog = 0.f, summ2 = 0.f;
#pragma unroll
        for (int f = 0; f < FF; ++f) {
            float v = in_var[bk * FF + f];
            float m = in_means[bk * FF + f];
            float ic = 1.f / (v + 1e-6f);
            dk[f] = ic * m;
            ek[f] = -0.5f * ic;
            sumlog += logf(6.283185307179586f * v);
            summ2  += ic * m * m;
        }
        Ak = logf(in_pi[bk]) - 0.5f * sumlog - 0.5f * summ2;
    } else {
        Ak = (ws + WS_A)[bk];
#pragma unroll
        for (int f = 0; f < FF; ++f) {
            dk[f] = (ws + WS_D)[bk * FF + f];
            ek[f] = (ws + WS_E)[bk * FF + f];
        }
    }

    // shfl sources: same point j, the other 4 clusters (stride 12 inside [0,60))
    const int src1 = j + PPT * ((g + 1) % KK);
    const int src2 = j + PPT * ((g + 2) % KK);
    const int src3 = j + PPT * ((g + 3) % KK);
    const int src4 = j + PPT * ((g + 4) % KK);

    constexpr bool ACC = (MODE != 3);
    float s0a = 0.f, s1[FF], s2[FF];
    if (ACC) {
#pragma unroll
        for (int f = 0; f < FF; ++f) { s1[f] = 0.f; s2[f] = 0.f; }
    }

    const float* dbase = data + (size_t)b * NPTS * FF;
    float pf_hold = 0.f;   // prefetch touch consumed one iteration late (r5 lesson)

    for (int t = wv; t < NT12; t += WPB) {
        const int p  = t * PPT + j;
        const int pc = (p < NPTS) ? p : (NPTS - 1);      // tail clamp
        const float* xp = dbase + (size_t)pc * FF;
        float4 xa = ((const float4*)xp)[0];
        float4 xb = ((const float4*)xp)[1];
        float4 xc = ((const float4*)xp)[2];
        float4 xd = ((const float4*)xp)[3];
        float4 xe = ((const float4*)xp)[4];

        // touch next tile (one b32 per lane), stays in flight a full iteration
        float pf = 0.f;
        const int tn = t + WPB;
        if (tn < NT12) {
            int pn = tn * PPT + j;
            if (pn >= NPTS) pn = NPTS - 1;
            pf = dbase[(size_t)pn * FF];
        }

        float x[FF];
        x[0]=xa.x; x[1]=xa.y; x[2]=xa.z; x[3]=xa.w;
        x[4]=xb.x; x[5]=xb.y; x[6]=xb.z; x[7]=xb.w;
        x[8]=xc.x; x[9]=xc.y; x[10]=xc.z; x[11]=xc.w;
        x[12]=xd.x; x[13]=xd.y; x[14]=xd.z; x[15]=xd.w;
        x[16]=xe.x; x[17]=xe.y; x[18]=xe.z; x[19]=xe.w;

        float za = 0.f, zb = 0.f;     // two fma chains for ILP
#pragma unroll
        for (int f = 0; f < FF; f += 2) {
            za = fmaf(x[f],     fmaf(ek[f],     x[f],     dk[f]),     za);
            zb = fmaf(x[f + 1], fmaf(ek[f + 1], x[f + 1], dk[f + 1]), zb);
        }
        const float z = Ak + za + zb;

        // in-wave 5-cluster softmax: 4 shfl for max, 4 shfl for sum
        float mx = z;
        mx = fmaxf(mx, __shfl(z, src1));
        mx = fmaxf(mx, __shfl(z, src2));
        mx = fmaxf(mx, __shfl(z, src3));
        mx = fmaxf(mx, __shfl(z, src4));
        const float e = __expf(z - mx);
        float sum = e;
        sum += __shfl(e, src1);
        sum += __shfl(e, src2);
        sum += __shfl(e, src3);
        sum += __shfl(e, src4);
        float post = e / sum;

        const bool valid = act && (p < NPTS);
        if (!ACC) {
            if (valid) {
                size_t o = ((size_t)b * NPTS + p) * KK + g;
                out_ll[o]   = z;
                out_post[o] = post;
            }
        } else {
            post = valid ? post : 0.f;
            s0a += post;
#pragma unroll
            for (int f = 0; f < FF; ++f) {
                float px = post * x[f];
                s1[f] += px;
                s2[f] = fmaf(px, x[f], s2[f]);
            }
        }
        asm volatile("" :: "v"(pf_hold));   // consume PREVIOUS touch (counted wait)
        pf_hold = pf;
    }
    asm volatile("" :: "v"(pf_hold));

    if (ACC) {
        // reduce the 12 contiguous lanes of each cluster group; result at j==0.
        // step1: v += v(+4) + v(+8)  (valid at i<4)
        // step2: v += v(+2)          (valid at i<2)
        // step3: v += v(+1)          (valid at i==0 -> full 12-lane sum)
#define RED12(v) { float _t1 = __shfl_down(v, 4), _t2 = __shfl_down(v, 8); \
                   v += _t1 + _t2; v += __shfl_down(v, 2); v += __shfl_down(v, 1); }
        RED12(s0a);
#pragma unroll
        for (int f = 0; f < FF; ++f) { RED12(s1[f]); RED12(s2[f]); }
#undef RED12
        if (act && j == 0) {
            float* row = pout + ((size_t)bk * WPB + wv) * PSTRIDE;
#pragma unroll
            for (int f = 0; f < FF; ++f) { row[f] = s1[f]; row[FF + f] = s2[f]; }
            row[2 * FF] = s0a;
        }
    }
}

// ---- reduce partials + M-step: writes ws coefs; final call also om/ov/op ----
__global__ __launch_bounds__(512) void update_kernel(const float* __restrict__ partials,
                                                     float* __restrict__ ws,
                                                     float* __restrict__ om,
                                                     float* __restrict__ ov,
                                                     float* __restrict__ op,
                                                     int write_params) {
    __shared__ float shA[8][PSTRIDE];
    __shared__ float shB[8 * KK];
    const int bk   = blockIdx.x;          // b*KK + k
    const int b    = bk / KK;
    const int tid  = threadIdx.x;
    const int w8   = tid >> 6;
    const int lane = tid & 63;

    // phase A: lane l sums slot l over rows w8..WPB step 8 (2 split chains)
    if (lane < PSTRIDE) {
        const float* base = partials + (size_t)bk * WPB * PSTRIDE + lane;
        float a0 = 0.f, a1 = 0.f;
        for (int gg = w8; gg < WPB; gg += 16) {
            a0 += base[(size_t)gg * PSTRIDE];
            a1 += base[(size_t)(gg + 8) * PSTRIDE];
        }
        shA[w8][lane] = a0 + a1;
    }
    // phase B: total cluster sizes over all K clusters (pi normalizer)
    if (tid < 8 * KK) {
        const int kp = tid >> 3, jx = tid & 7;
        const float* cb = partials + (size_t)(b * KK + kp) * WPB * PSTRIDE + 2 * FF;
        float s = 0.f;
        for (int gg = jx; gg < WPB; gg += 8) s += cb[(size_t)gg * PSTRIDE];
        shB[tid] = s;
    }
    __syncthreads();

    if (tid < 64) {
        float svt = 0.f;
        if (lane < PSTRIDE) {
            svt = (shA[0][lane] + shA[1][lane]) + (shA[2][lane] + shA[3][lane])
                + (shA[4][lane] + shA[5][lane]) + (shA[6][lane] + shA[7][lane]);
        }

        float tb = (lane < 8 * KK) ? shB[lane] : 0.f;
#pragma unroll
        for (int off = 32; off > 0; off >>= 1) tb += __shfl_xor(tb, off);
        // tb = Sum_k s0_k on every lane

        float s0  = __shfl(svt, 2 * FF);
        float den = s0 + 1e-7f;
        float m   = svt / den;                     // lanes 0..19: S1[f]/den
        float s2f = __shfl(svt, FF + (lane % FF)); // S2[f]
        float var = (s2f - 2.f * m * svt + m * m * s0) / den + 1e-6f;

        if (write_params && lane < FF) {
            om[bk * FF + lane] = m;
            ov[bk * FF + lane] = var;
        }

        float pr = (s0 / (float)NPTS) / fmaxf(tb / (float)NPTS, 1e-12f);
        if (write_params && lane == 0) op[bk] = pr;

        float ic = 1.f / (var + 1e-6f);
        if (lane < FF) {
            (ws + WS_D)[bk * FF + lane] = ic * m;
            (ws + WS_E)[bk * FF + lane] = -0.5f * ic;
        }
        float t1 = (lane < FF) ? logf(6.283185307179586f * var) : 0.f;
        float t2 = (lane < FF) ? ic * m * m : 0.f;
#pragma unroll
        for (int off = 1; off < 64; off <<= 1) {
            t1 += __shfl_xor(t1, off);
            t2 += __shfl_xor(t2, off);
        }
        if (lane == 0)
            (ws + WS_A)[bk] = logf(pr) - 0.5f * t1 - 0.5f * t2;
    }
}

extern "C" void kernel_launch(void* const* d_in, const int* in_sizes, int n_in,
                              void* d_out, int out_size, void* d_ws, size_t ws_size,
                              hipStream_t stream) {
    const float* data     = (const float*)d_in[0];
    const float* in_means = (const float*)d_in[1];
    const float* in_var   = (const float*)d_in[2];
    const float* in_pi    = (const float*)d_in[3];
    float* ws  = (float*)d_ws;
    float* out = (float*)d_out;

    float* out_ll   = out;
    float* out_post = out + (size_t)BB * NPTS * KK;
    float* om       = out + 2 * (size_t)BB * NPTS * KK;
    float* ov       = om + BB * KK * FF;
    float* op       = ov + BB * KK * FF;

    // partials [BB][KK][WPB][PSTRIDE] = 3.93 MB, lives in the not-yet-needed
    // ll output region (12.8 MB); the final E-step fully overwrites it.
    float* P = out_ll;

    // it0: coefs from inputs (in-kernel), accumulate -> P
    estep_kernel<0><<<BB * GB, 256, 0, stream>>>(data, in_means, in_var, in_pi,
                                                 ws, P, nullptr, nullptr);
    // it1..4: update params from P, then estep with ws coefs
    for (int it = 1; it < 5; ++it) {
        update_kernel<<<BB * KK, 512, 0, stream>>>(P, ws, om, ov, op, 0);
        estep_kernel<1><<<BB * GB, 256, 0, stream>>>(data, nullptr, nullptr, nullptr,
                                                     ws, P, nullptr, nullptr);
    }
    // final M-step: writes om/ov/op + ws coefs for the output pass
    update_kernel<<<BB * KK, 512, 0, stream>>>(P, ws, om, ov, op, 1);
    // final E-step: write ll/post with post-loop params
    estep_kernel<3><<<BB * GB, 256, 0, stream>>>(data, nullptr, nullptr, nullptr,
                                                 ws, nullptr, out_ll, out_post);
}

// Round 8
// 319.310 us; speedup vs baseline: 1.1959x; 1.1502x over previous
//
#include <hip/hip_runtime.h>
#include <math.h>

#define BB 8
#define NPTS 80000
#define KK 5
#define FF 20
#define GG 128                 // blocks per batch -> 1024 blocks = 4 blocks/CU
#define TILE 64                // one point per lane
#define NTILES (NPTS / TILE)   // 1250, exact
#define PSTRIDE 48             // padded partial row: 20 s1 + 20 s2 + 1 s0 + pad

// workspace layout (float offsets) -- small params/coefs only
#define WS_A  0      // [BB*KK]
#define WS_D  40     // [BB*KK*FF]
#define WS_E  840    // [BB*KK*FF]

// async global->LDS, 16B per lane (HW: wave-uniform LDS base + lane*16, global
// source per-lane). The compiler NEVER emits this on its own (guide CM#1).
#define STAGE(ldsp, gp)                                                        \
    __builtin_amdgcn_global_load_lds(                                          \
        (const __attribute__((address_space(1))) void*)(const void*)(gp),      \
        (__attribute__((address_space(3))) void*)(void*)(ldsp), 16, 0, 0)

// ---- compute A/d/e from (means,var,pi) ----
__global__ void prepare_kernel(const float* __restrict__ means, const float* __restrict__ var,
                               const float* __restrict__ pi, float* __restrict__ ws) {
    int t = (int)threadIdx.x;
    if (t < BB * KK) {
        float sumlog = 0.f, summ2 = 0.f;
        for (int f = 0; f < FF; ++f) {
            float v = var[t * FF + f];
            float m = means[t * FF + f];
            float ic = 1.f / (v + 1e-6f);
            sumlog += logf(6.283185307179586f * v);
            summ2  += ic * m * m;
            (ws + WS_D)[t * FF + f] = ic * m;
            (ws + WS_E)[t * FF + f] = -0.5f * ic;
        }
        (ws + WS_A)[t] = logf(pi[t]) - 0.5f * sumlog - 0.5f * summ2;
    }
}

// ---- E-step: T3 pipeline. global_load_lds 2 tiles ahead, 4-slot LDS ring,
// ONE raw barrier per tile with counted vmcnt(1) (stage never drained).
// Race windows (slot s = it&3): read(iter k) -> rewrite(iter k+2) spans the
// k+1 barrier; stage(iter k) -> vmcnt(1)@k+1 barrier -> read(iter k+2). Safe.
// xs layout is point-major [pt][f] (gload_lds is linear); b128 reads at
// lane*80B distribute 8 lanes per bank-quad = uniform 8-pass (b128 floor).
template <bool WRITE_OUT>
__global__ __launch_bounds__(320) void estep_kernel(const float* __restrict__ data,
                                                    const float* __restrict__ ws,
                                                    float* __restrict__ partials,
                                                    float* __restrict__ out_ll,
                                                    float* __restrict__ out_post) {
    __shared__ float xs[4][TILE * FF];     // 4 x 5120 B ring
    __shared__ float lls[2][KK][TILE];     // 2.5 KB z-exchange, double-buffered

    const int b    = blockIdx.x / GG;
    const int g    = blockIdx.x % GG;
    const int tid  = threadIdx.x;
    const int w    = __builtin_amdgcn_readfirstlane(tid >> 6);   // cluster, wave-uniform
    const int lane = tid & 63;

    const float Ak = (ws + WS_A)[b * KK + w];
    float dk[FF], ek[FF];                  // wave-uniform -> SGPRs
#pragma unroll
    for (int f = 0; f < FF; ++f) {
        dk[f] = (ws + WS_D)[(b * KK + w) * FF + f];
        ek[f] = (ws + WS_E)[(b * KK + w) * FF + f];
    }

    float s0 = 0.f, s1[FF], s2[FF];
    if (!WRITE_OUT) {
#pragma unroll
        for (int f = 0; f < FF; ++f) { s1[f] = 0.f; s2[f] = 0.f; }
    }

    const float* dbase = data + (size_t)b * NPTS * FF;
    const int toff = tid * 4;              // 16B unit per thread (320*16B = 5120B)

    // prologue: stage tiles g (slot0) and g+GG (slot1); drain once; barrier.
    STAGE(&xs[0][toff], dbase + (size_t)g * TILE * FF + toff);
    STAGE(&xs[1][toff], dbase + (size_t)(g + GG) * TILE * FF + toff);   // g+128 < 1250 always
    asm volatile("s_waitcnt vmcnt(0)" ::: "memory");
    __syncthreads();

    int cur = 0, pb = 0;
    for (int t = g; t < NTILES; t += GG) {
        // stage tile t+2GG into slot (cur+2)&3
        const int t2 = t + 2 * GG;                     // block-uniform
        if (t2 < NTILES) {
            const int nx2 = (cur + 2) & 3;
            STAGE(&xs[nx2][toff], dbase + (size_t)t2 * TILE * FF + toff);
        }

        // z phase: 5 x ds_read_b128 of this lane's point, consumed 4-at-a-time
        const float4* xr = (const float4*)&xs[cur][lane * FF];
        float4 v0 = xr[0], v1 = xr[1], v2 = xr[2], v3 = xr[3], v4 = xr[4];
        float xz[FF];
        xz[0]=v0.x; xz[1]=v0.y; xz[2]=v0.z; xz[3]=v0.w;
        xz[4]=v1.x; xz[5]=v1.y; xz[6]=v1.z; xz[7]=v1.w;
        xz[8]=v2.x; xz[9]=v2.y; xz[10]=v2.z; xz[11]=v2.w;
        xz[12]=v3.x; xz[13]=v3.y; xz[14]=v3.z; xz[15]=v3.w;
        xz[16]=v4.x; xz[17]=v4.y; xz[18]=v4.z; xz[19]=v4.w;
        float za = 0.f, zb = 0.f;
#pragma unroll
        for (int f = 0; f < FF; f += 2) {
            za = fmaf(xz[f],     fmaf(ek[f],     xz[f],     dk[f]),     za);
            zb = fmaf(xz[f + 1], fmaf(ek[f + 1], xz[f + 1], dk[f + 1]), zb);
        }
        lls[pb][w][lane] = Ak + za + zb;

        // THE barrier: lls visible (lgkmcnt 0), previous-iter stage complete
        // (vmcnt<=1: only the just-issued stage may remain in flight).
        if (t2 < NTILES)
            asm volatile("s_waitcnt vmcnt(1) lgkmcnt(0)\n\ts_barrier" ::: "memory");
        else
            asm volatile("s_waitcnt vmcnt(0) lgkmcnt(0)\n\ts_barrier" ::: "memory");

        // softmax across the 5 clusters of this point
        float l0 = lls[pb][0][lane], l1 = lls[pb][1][lane], l2 = lls[pb][2][lane],
              l3 = lls[pb][3][lane], l4 = lls[pb][4][lane];
        float mx = fmaxf(fmaxf(fmaxf(l0, l1), fmaxf(l2, l3)), l4);
        float e0 = __expf(l0 - mx), e1 = __expf(l1 - mx), e2 = __expf(l2 - mx),
              e3 = __expf(l3 - mx), e4 = __expf(l4 - mx);
        float inv = 1.f / (e0 + e1 + e2 + e3 + e4);
        float ew  = (w == 0) ? e0 : (w == 1) ? e1 : (w == 2) ? e2 : (w == 3) ? e3 : e4;
        float post = ew * inv;
        float z = (w == 0) ? l0 : (w == 1) ? l1 : (w == 2) ? l2 : (w == 3) ? l3 : l4;

        if (WRITE_OUT) {
            size_t o = ((size_t)b * NPTS + (size_t)t * TILE + lane) * KK + w;
            out_ll[o]   = z;
            out_post[o] = post;
        } else {
            s0 += post;
            // re-read x post-barrier (asm memory clobber blocks CSE with the
            // z-phase loads) so x liveness doesn't span the barrier -> low VGPR
            const float4* xr2 = (const float4*)&xs[cur][lane * FF];
#pragma unroll
            for (int j = 0; j < 5; ++j) {
                float4 u = xr2[j];
                float p0 = post * u.x, p1 = post * u.y,
                      p2 = post * u.z, p3 = post * u.w;
                s1[4*j]   += p0;  s2[4*j]   = fmaf(p0, u.x, s2[4*j]);
                s1[4*j+1] += p1;  s2[4*j+1] = fmaf(p1, u.y, s2[4*j+1]);
                s1[4*j+2] += p2;  s2[4*j+2] = fmaf(p2, u.z, s2[4*j+2]);
                s1[4*j+3] += p3;  s2[4*j+3] = fmaf(p3, u.w, s2[4*j+3]);
            }
        }
        cur = (cur + 1) & 3;
        pb ^= 1;
    }

    if (!WRITE_OUT) {
#pragma unroll
        for (int off = 32; off > 0; off >>= 1) {
            s0 += __shfl_down(s0, off);
#pragma unroll
            for (int f = 0; f < FF; ++f) {
                s1[f] += __shfl_down(s1[f], off);
                s2[f] += __shfl_down(s2[f], off);
            }
        }
        if (lane == 0) {
            // unique row per (b,k,g): plain stores, zero contention
            float* row = partials + ((size_t)(b * KK + w) * GG + g) * PSTRIDE;
#pragma unroll
            for (int f = 0; f < FF; ++f) { row[f] = s1[f]; row[FF + f] = s2[f]; }
            row[2 * FF] = s0;
        }
    }
}

// ---- reduce partials + M-step + next-iteration coefs ----
// One block per (b,k) = 40 blocks, 512 threads: 8 waves split the g-reduction
// 8-way; 40 extra threads redundantly sum the s0 column of ALL K clusters for
// the pi normalizer, so no cross-block exchange is needed.
__global__ __launch_bounds__(512) void update_kernel(const float* __restrict__ partials,
                                                     float* __restrict__ ws,
                                                     float* __restrict__ om,
                                                     float* __restrict__ ov,
                                                     float* __restrict__ op,
                                                     int write_params) {
    __shared__ float shA[8][PSTRIDE];
    __shared__ float shB[8 * KK];
    const int bk   = blockIdx.x;          // b*KK + k
    const int b    = bk / KK;
    const int tid  = threadIdx.x;
    const int w8   = tid >> 6;
    const int lane = tid & 63;

    if (lane < PSTRIDE) {
        const float* base = partials + (size_t)bk * GG * PSTRIDE + lane;
        float sv = 0.f;
        for (int gg = w8; gg < GG; gg += 8) sv += base[(size_t)gg * PSTRIDE];
        shA[w8][lane] = sv;
    }
    if (tid < 8 * KK) {
        const int kp = tid >> 3, j = tid & 7;
        const float* cb = partials + (size_t)(b * KK + kp) * GG * PSTRIDE + 2 * FF;
        float s = 0.f;
        for (int gg = j; gg < GG; gg += 8) s += cb[(size_t)gg * PSTRIDE];
        shB[tid] = s;
    }
    __syncthreads();

    if (tid < 64) {
        float svt = 0.f;
        if (lane < PSTRIDE) {
            svt = (shA[0][lane] + shA[1][lane]) + (shA[2][lane] + shA[3][lane])
                + (shA[4][lane] + shA[5][lane]) + (shA[6][lane] + shA[7][lane]);
        }

        float tb = (lane < 8 * KK) ? shB[lane] : 0.f;
#pragma unroll
        for (int off = 32; off > 0; off >>= 1) tb += __shfl_xor(tb, off);
        // tb = Sum_k s0_k on every lane

        float s0  = __shfl(svt, 2 * FF);          // this cluster's size
        float den = s0 + 1e-7f;
        float m   = svt / den;                    // lanes 0..19: S1[f]/den
        float s2f = __shfl(svt, FF + (lane % FF));// S2[f]
        float var = (s2f - 2.f * m * svt + m * m * s0) / den + 1e-6f;

        if (write_params && lane < FF) {
            om[bk * FF + lane] = m;
            ov[bk * FF + lane] = var;
        }

        float pr = (s0 / (float)NPTS) / fmaxf(tb / (float)NPTS, 1e-12f);
        if (write_params && lane == 0) op[bk] = pr;

        float ic = 1.f / (var + 1e-6f);
        if (lane < FF) {
            (ws + WS_D)[bk * FF + lane] = ic * m;
            (ws + WS_E)[bk * FF + lane] = -0.5f * ic;
        }
        float t1 = (lane < FF) ? logf(6.283185307179586f * var) : 0.f;
        float t2 = (lane < FF) ? ic * m * m : 0.f;
#pragma unroll
        for (int off = 1; off < 64; off <<= 1) {
            t1 += __shfl_xor(t1, off);
            t2 += __shfl_xor(t2, off);
        }
        if (lane == 0)
            (ws + WS_A)[bk] = logf(pr) - 0.5f * t1 - 0.5f * t2;
    }
}

extern "C" void kernel_launch(void* const* d_in, const int* in_sizes, int n_in,
                              void* d_out, int out_size, void* d_ws, size_t ws_size,
                              hipStream_t stream) {
    const float* data     = (const float*)d_in[0];
    const float* in_means = (const float*)d_in[1];
    const float* in_var   = (const float*)d_in[2];
    const float* in_pi    = (const float*)d_in[3];
    float* ws  = (float*)d_ws;
    float* out = (float*)d_out;

    float* out_ll   = out;
    float* out_post = out + (size_t)BB * NPTS * KK;
    float* om       = out + 2 * (size_t)BB * NPTS * KK;
    float* ov       = om + BB * KK * FF;
    float* op       = ov + BB * KK * FF;

    // partial-sum buffer (983 KB) lives in the not-yet-needed ll output region;
    // the final E-step fully overwrites it.
    float* P = out_ll;

    prepare_kernel<<<1, 64, 0, stream>>>(in_means, in_var, in_pi, ws);

    for (int it = 0; it < 5; ++it) {
        estep_kernel<false><<<BB * GG, 320, 0, stream>>>(data, ws, P,
                                                         nullptr, nullptr);
        update_kernel<<<BB * KK, 512, 0, stream>>>(P, ws, om, ov, op,
                                                   (it == 4) ? 1 : 0);
    }
    // final E-step with post-loop params: write ll/post outputs
    estep_kernel<true><<<BB * GG, 320, 0, stream>>>(data, ws, nullptr,
                                                    out_ll, out_post);
}